// Round 9
// baseline (136.285 us; speedup 1.0000x reference)
//
#include <hip/hip_runtime.h>
#include <hip/hip_bf16.h>

// Chamfer distance between two (1,16384,3) fp32 clouds, via split-bf16
// augmented GEMM on the matrix cores:
//   A_enc[p] . B_enc[q] = |x_p|^2 + |y_q|^2 - 2 x_p.y_q = d^2(p,q)   (err ~3e-5)
// One v_mfma_f32_32x32x16_bf16 = 1024 d^2 entries; min-accumulate in C regs.
//
// V9: kill the per-wave serial chain. Counter recalibration on V5/V8 shows
// VALUBusy/MfmaUtil are sum-over-SIMD normalized and the fold/MFMA accounting
// closes EXACTLY -> no parasitic VALU, no AGPR shuttle; walls = per-wave
// serial latency x sequential waves (L2 round-trip per iteration, barely any
// inter-wave overlap; V8: 2.5x occupancy made it WORSE as per-wave work rose).
// Fixes, keeping V7's verified arithmetic (passed, absmax 0.0):
//  - register double-buffer: load 8 B-frags while 16 MFMAs + folds run on the
//    other 8 -> load latency hidden INSIDE each wave. Fully static indexing.
//  - XCD swizzle: all 64 row-blocks of a (seg,dir) pinned to one XCD; each
//    XCD L2 serves 2 hot 64KB segments (no cross-XCD duplication/thrash).
//  - native 32x32x16 (half of V8's MFMA count and load bytes).
// Floor: fold 16.4k cy/SIMD ~ 6.8us; MFMA pipe 16.4k cy/CU overlapped.

constexpr int P      = 16384;
constexpr int BLK    = 256;
constexpr int NSEG   = 8;             // column segments per direction
constexpr int SEGPTS = P / NSEG;      // 2048 cols per block
constexpr int ROWSB  = 256;           // rows per block (4 waves x 2 strips x 32)
constexpr int CLOUDB = P * 32;        // bytes of encodings per cloud (512 KB)

typedef short s8v  __attribute__((ext_vector_type(8)));
typedef float f16v __attribute__((ext_vector_type(16)));

static __device__ inline unsigned short bf16r(float f) {   // RNE fp32->bf16
    unsigned u = __float_as_uint(f);
    u = (u + 0x7FFFu + ((u >> 16) & 1u)) >> 16;
    return (unsigned short)u;
}
static __device__ inline float bf2f(unsigned short h) {
    return __uint_as_float(((unsigned)h) << 16);
}

// A-side encoding, packed as 8 uints (16 bf16 slots, little-end first).
static __device__ inline void encA(float a, float b, float c, unsigned e[8]) {
    const unsigned ONE = 0x3F80u;
    const float s = fmaf(a, a, fmaf(b, b, c * c));
    const unsigned short ah = bf16r(a), bh = bf16r(b), ch = bf16r(c);
    const unsigned short al = bf16r(a - bf2f(ah));
    const unsigned short bl = bf16r(b - bf2f(bh));
    const unsigned short cl = bf16r(c - bf2f(ch));
    const unsigned short sh = bf16r(s), sl = bf16r(s - bf2f(sh));
    e[0] = ah | ((unsigned)al << 16);   // k0,k1
    e[1] = bh | ((unsigned)bl << 16);   // k2,k3
    e[2] = ch | ((unsigned)cl << 16);   // k4,k5
    e[3] = ah | ((unsigned)bh << 16);   // k6,k7
    e[4] = ch | ((unsigned)sh << 16);   // k8,k9
    e[5] = sl | (ONE << 16);            // k10,k11
    e[6] = ONE;                         // k12,k13(=0)
    e[7] = 0;                           // k14,k15
}

// B-side encoding (-2 folded in; all scalings exact in bf16).
static __device__ inline void encB(float a, float b, float c, unsigned e[8]) {
    const unsigned ONE = 0x3F80u;
    const float s = fmaf(a, a, fmaf(b, b, c * c));
    const unsigned short ah = bf16r(a), bh = bf16r(b), ch = bf16r(c);
    const unsigned short al = bf16r(a - bf2f(ah));
    const unsigned short bl = bf16r(b - bf2f(bh));
    const unsigned short cl = bf16r(c - bf2f(ch));
    const unsigned short sh = bf16r(s), sl = bf16r(s - bf2f(sh));
    const unsigned short Ah = bf16r(-2.f * bf2f(ah)), Bh = bf16r(-2.f * bf2f(bh));
    const unsigned short Ch = bf16r(-2.f * bf2f(ch));
    const unsigned short Al = bf16r(-2.f * bf2f(al)), Bl = bf16r(-2.f * bf2f(bl));
    const unsigned short Cl = bf16r(-2.f * bf2f(cl));
    e[0] = Ah | ((unsigned)Ah << 16);   // k0,k1
    e[1] = Bh | ((unsigned)Bh << 16);   // k2,k3
    e[2] = Ch | ((unsigned)Ch << 16);   // k4,k5
    e[3] = Al | ((unsigned)Bl << 16);   // k6,k7
    e[4] = Cl | (ONE << 16);            // k8,k9
    e[5] = ONE | ((unsigned)sh << 16);  // k10,k11
    e[6] = sl;                          // k12,k13(=0)
    e[7] = 0;                           // k14,k15
}

// ---- precompute: encode all 2x16384 points once ---------------------------
// encAbuf layout: cloud*CLOUDB + p*32 + half*16              (per-lane frag read)
// encBbuf layout: cloud*CLOUDB + (p>>5)*1024 + (p&31)*16 (+512 for k-half 1)
//                 -> B-frag for tile t, lane l = base + t*1024 + l*16.
__global__ __launch_bounds__(BLK) void encode_pts(
    const float* __restrict__ pc1, const float* __restrict__ pc2,
    unsigned char* __restrict__ encAbuf, unsigned char* __restrict__ encBbuf,
    float* __restrict__ out)
{
    const int gid = blockIdx.x * BLK + threadIdx.x;   // 0 .. 2P-1
    if (gid == 0) out[0] = 0.0f;
    const int c = gid >> 14;                          // cloud
    const int p = gid & (P - 1);
    const float* src = c ? pc2 : pc1;
    const float x = src[3 * p], y = src[3 * p + 1], z = src[3 * p + 2];

    unsigned ea[8], eb[8];
    encA(x, y, z, ea);
    encB(x, y, z, eb);

    unsigned char* ap = encAbuf + (size_t)c * CLOUDB + (size_t)p * 32;
    *(uint4*)(ap)      = make_uint4(ea[0], ea[1], ea[2], ea[3]);
    *(uint4*)(ap + 16) = make_uint4(ea[4], ea[5], ea[6], ea[7]);

    unsigned char* bp = encBbuf + (size_t)c * CLOUDB + (size_t)(p >> 5) * 1024
                        + (size_t)(p & 31) * 16;
    *(uint4*)(bp)       = make_uint4(eb[0], eb[1], eb[2], eb[3]);
    *(uint4*)(bp + 512) = make_uint4(eb[4], eb[5], eb[6], eb[7]);
}

// ---- main: per (rowgroup, segment, dir) strip-sweep GEMM with min-acc ------
__global__ __launch_bounds__(BLK) void chamfer_mfma(
    const unsigned char* __restrict__ encAbuf,
    const unsigned char* __restrict__ encBbuf,
    float* __restrict__ part)       // [2][NSEG][P], every slot written once
{
    // XCD-locality swizzle: blockIdx.x -> XCD is round-robin (id % 8).
    // Give each XCD 2 whole (seg,dir) combos so its L2 holds 2 hot segments.
    const int wgid  = blockIdx.x;         // 0..1023
    const int xcd   = wgid & 7;
    const int slot  = wgid >> 3;          // 0..127
    const int combo = xcd * 2 + (slot >> 6);   // 0..15, bijective
    const int bx    = slot & 63;          // 0..63 row-group
    const int seg   = combo & 7;
    const int dir   = combo >> 3;

    const int acloud = dir;          // dir0: rows from pc1
    const int bcloud = dir ^ 1;      // dir0: cols from pc2

    const int tid  = threadIdx.x;
    const int lane = tid & 63;
    const int wv   = tid >> 6;
    const int l31  = lane & 31;
    const int half = lane >> 5;          // k-half for A/B frags

    // ---- A fragments: 2 strips of 32 rows per wave, loaded once ----
    const int rowbase = bx * ROWSB + wv * 64;
    const unsigned char* abase = encAbuf + (size_t)acloud * CLOUDB + (size_t)half * 16;
    const s8v afrag0 = *(const s8v*)(abase + (size_t)(rowbase + l31) * 32);
    const s8v afrag1 = *(const s8v*)(abase + (size_t)(rowbase + 32 + l31) * 32);

    f16v acc0, acc1, Z;
    #pragma unroll
    for (int i = 0; i < 16; ++i) { acc0[i] = 3.0e38f; acc1[i] = 3.0e38f; Z[i] = 0.0f; }

    // ---- sweep 2048 cols = 64 tiles, in register-double-buffered groups of 8
    const unsigned char* bp = encBbuf + (size_t)bcloud * CLOUDB
                              + (size_t)(seg * SEGPTS) * 32
                              + (size_t)lane * 16;

    auto compute = [&](const s8v* X) {
        #pragma unroll
        for (int k = 0; k < 8; k += 2) {
            const f16v d0a = __builtin_amdgcn_mfma_f32_32x32x16_bf16(afrag0, X[k],     Z, 0, 0, 0);
            const f16v d0b = __builtin_amdgcn_mfma_f32_32x32x16_bf16(afrag0, X[k + 1], Z, 0, 0, 0);
            #pragma unroll
            for (int i = 0; i < 16; ++i)
                acc0[i] = fminf(acc0[i], fminf(d0a[i], d0b[i]));
            const f16v d1a = __builtin_amdgcn_mfma_f32_32x32x16_bf16(afrag1, X[k],     Z, 0, 0, 0);
            const f16v d1b = __builtin_amdgcn_mfma_f32_32x32x16_bf16(afrag1, X[k + 1], Z, 0, 0, 0);
            #pragma unroll
            for (int i = 0; i < 16; ++i)
                acc1[i] = fminf(acc1[i], fminf(d1a[i], d1b[i]));
        }
    };

    s8v Abuf[8], Bbuf[8];
    #pragma unroll
    for (int k = 0; k < 8; ++k)
        Abuf[k] = *(const s8v*)(bp + k * 1024);

    #pragma unroll 1
    for (int g = 0; g < 8; g += 2) {
        // issue group g+1 loads, then compute group g (latency hidden in-wave)
        #pragma unroll
        for (int k = 0; k < 8; ++k)
            Bbuf[k] = *(const s8v*)(bp + ((g + 1) * 8 + k) * 1024);
        compute(Abuf);
        if (g + 2 < 8) {
            #pragma unroll
            for (int k = 0; k < 8; ++k)
                Abuf[k] = *(const s8v*)(bp + ((g + 2) * 8 + k) * 1024);
        }
        compute(Bbuf);
    }

    // ---- fold over the 32 columns held across lanes; write per-row min ----
    // C/D layout (verified): col=lane&31, row=(reg&3)+8*(reg>>2)+4*(lane>>5)
    float* pbase = part + ((size_t)(dir * NSEG + seg)) * P;
    #pragma unroll
    for (int s = 0; s < 2; ++s) {
        #pragma unroll
        for (int rg = 0; rg < 16; ++rg) {
            float v = s ? acc1[rg] : acc0[rg];
            v = fminf(v, __shfl_xor(v, 1, 64));
            v = fminf(v, __shfl_xor(v, 2, 64));
            v = fminf(v, __shfl_xor(v, 4, 64));
            v = fminf(v, __shfl_xor(v, 8, 64));
            v = fminf(v, __shfl_xor(v, 16, 64));
            if (l31 == 0) {
                const int row = rowbase + s * 32 + (rg & 3) + 8 * (rg >> 2) + 4 * half;
                pbase[row] = v;
            }
        }
    }
}

// ---- reduce: min over segments, threshold, mean, atomic sum ----------------
__global__ __launch_bounds__(BLK) void chamfer_reduce(
    const float* __restrict__ part, float* __restrict__ out)
{
    const int gid = blockIdx.x * BLK + threadIdx.x;   // 0 .. 2P-1
    const int dirbase = (gid >= P) ? NSEG * P : 0;
    const int row = gid & (P - 1);

    float m = part[dirbase + row];
    #pragma unroll
    for (int s = 1; s < NSEG; ++s) m = fminf(m, part[dirbase + s * P + row]);

    if (m >= 2.0f) m = 0.0f;                  // DIST_THD mask
    float v = m * (1.0f / (float)P);          // point mean; batch N=1

    #pragma unroll
    for (int off = 32; off > 0; off >>= 1) v += __shfl_down(v, off, 64);

    __shared__ float wsum[BLK / 64];
    const int lane = threadIdx.x & 63;
    const int wvi = threadIdx.x >> 6;
    if (lane == 0) wsum[wvi] = v;
    __syncthreads();
    if (threadIdx.x == 0) {
        float ssum = wsum[0];
        #pragma unroll
        for (int w = 1; w < BLK / 64; ++w) ssum += wsum[w];
        atomicAdd(out, ssum);
    }
}

extern "C" void kernel_launch(void* const* d_in, const int* in_sizes, int n_in,
                              void* d_out, int out_size, void* d_ws, size_t ws_size,
                              hipStream_t stream) {
    const float* pc1 = (const float*)d_in[0];
    const float* pc2 = (const float*)d_in[1];
    float* out = (float*)d_out;
    unsigned char* ws = (unsigned char*)d_ws;
    float* part = (float*)ws;                           // [2][8][P] = 1 MB
    unsigned char* encBbuf = ws + (1u << 20);           // 1 MB
    unsigned char* encAbuf = ws + (2u << 20);           // 1 MB

    encode_pts<<<(2 * P) / BLK, BLK, 0, stream>>>(pc1, pc2, encAbuf, encBbuf, out);

    chamfer_mfma<<<dim3(1024), BLK, 0, stream>>>(encAbuf, encBbuf, part);
    chamfer_reduce<<<(2 * P) / BLK, BLK, 0, stream>>>(part, out);
}

// Round 10
// 131.412 us; speedup vs baseline: 1.0371x; 1.0371x over previous
//
#include <hip/hip_runtime.h>
#include <hip/hip_bf16.h>

// Chamfer distance between two (1,16384,3) fp32 clouds, via split-bf16
// augmented GEMM on the matrix cores:
//   A_enc[p] . B_enc[q] = |x_p|^2 + |y_q|^2 - 2 x_p.y_q = d^2(p,q)   (err ~3e-5)
// One v_mfma_f32_32x32x16_bf16 = 1024 d^2 entries; min-accumulate in C regs.
//
// V10: SYMMETRIC — compute the d^2 matrix ONCE, reduce both directions.
// cham_x = row mins (as before); cham_y = col mins extracted from the same
// MFMA results (lane-local tree over the 32 regs covering the wave's 64 rows
// + shfl_xor(32) + one 128B store per tile into a per-wave part_y slice).
// Halves MFMAs, staging bytes, blocks, and per-wave iterations vs V4 — the
// best-measured structure (<=39us), which this otherwise copies verbatim:
// LDS staging, single 32KB round per block, native 32x32, 2 strips/wave.
// Record: V4<=39 < V5 45 (2 rounds) < V7 50 (no LDS) < V8 69 (16x16) <
// V9 86 (reg-dbuf, VGPR 200). All latency-bound (per-SIMD pipes <=15%).

constexpr int P      = 16384;
constexpr int BLK    = 256;
constexpr int NSEGC  = 16;            // column segments
constexpr int SEGPTS = P / NSEGC;     // 1024 cols per block (one LDS round)
constexpr int TILES  = SEGPTS / 32;   // 32 MFMA col-tiles per block
constexpr int ROWSB  = 256;           // rows per block (4 waves x 2 strips x 32)
constexpr int NROWB  = P / ROWSB;     // 64 row blocks
constexpr int NSLICE = NROWB * 4;     // 256 per-wave col-min slices
constexpr int CLOUDB = P * 32;        // 512 KB per encoding buffer

typedef short s8v  __attribute__((ext_vector_type(8)));
typedef float f16v __attribute__((ext_vector_type(16)));

static __device__ inline unsigned short bf16r(float f) {   // RNE fp32->bf16
    unsigned u = __float_as_uint(f);
    u = (u + 0x7FFFu + ((u >> 16) & 1u)) >> 16;
    return (unsigned short)u;
}
static __device__ inline float bf2f(unsigned short h) {
    return __uint_as_float(((unsigned)h) << 16);
}
// balanced 15-op min tree over a 16-reg MFMA result
static __device__ inline float tree16(const f16v d) {
    float a0 = fminf(d[0], d[1]),  a1 = fminf(d[2], d[3]);
    float a2 = fminf(d[4], d[5]),  a3 = fminf(d[6], d[7]);
    float a4 = fminf(d[8], d[9]),  a5 = fminf(d[10], d[11]);
    float a6 = fminf(d[12], d[13]), a7 = fminf(d[14], d[15]);
    a0 = fminf(a0, a1); a2 = fminf(a2, a3);
    a4 = fminf(a4, a5); a6 = fminf(a6, a7);
    a0 = fminf(a0, a2); a4 = fminf(a4, a6);
    return fminf(a0, a4);
}

// A-side encoding, packed as 8 uints (16 bf16 slots, little-end first).
static __device__ inline void encA(float a, float b, float c, unsigned e[8]) {
    const unsigned ONE = 0x3F80u;
    const float s = fmaf(a, a, fmaf(b, b, c * c));
    const unsigned short ah = bf16r(a), bh = bf16r(b), ch = bf16r(c);
    const unsigned short al = bf16r(a - bf2f(ah));
    const unsigned short bl = bf16r(b - bf2f(bh));
    const unsigned short cl = bf16r(c - bf2f(ch));
    const unsigned short sh = bf16r(s), sl = bf16r(s - bf2f(sh));
    e[0] = ah | ((unsigned)al << 16);   // k0,k1
    e[1] = bh | ((unsigned)bl << 16);   // k2,k3
    e[2] = ch | ((unsigned)cl << 16);   // k4,k5
    e[3] = ah | ((unsigned)bh << 16);   // k6,k7
    e[4] = ch | ((unsigned)sh << 16);   // k8,k9
    e[5] = sl | (ONE << 16);            // k10,k11
    e[6] = ONE;                         // k12,k13(=0)
    e[7] = 0;                           // k14,k15
}

// B-side encoding (-2 folded in; all scalings exact in bf16).
static __device__ inline void encB(float a, float b, float c, unsigned e[8]) {
    const unsigned ONE = 0x3F80u;
    const float s = fmaf(a, a, fmaf(b, b, c * c));
    const unsigned short ah = bf16r(a), bh = bf16r(b), ch = bf16r(c);
    const unsigned short al = bf16r(a - bf2f(ah));
    const unsigned short bl = bf16r(b - bf2f(bh));
    const unsigned short cl = bf16r(c - bf2f(ch));
    const unsigned short sh = bf16r(s), sl = bf16r(s - bf2f(sh));
    const unsigned short Ah = bf16r(-2.f * bf2f(ah)), Bh = bf16r(-2.f * bf2f(bh));
    const unsigned short Ch = bf16r(-2.f * bf2f(ch));
    const unsigned short Al = bf16r(-2.f * bf2f(al)), Bl = bf16r(-2.f * bf2f(bl));
    const unsigned short Cl = bf16r(-2.f * bf2f(cl));
    e[0] = Ah | ((unsigned)Ah << 16);   // k0,k1
    e[1] = Bh | ((unsigned)Bh << 16);   // k2,k3
    e[2] = Ch | ((unsigned)Ch << 16);   // k4,k5
    e[3] = Al | ((unsigned)Bl << 16);   // k6,k7
    e[4] = Cl | (ONE << 16);            // k8,k9
    e[5] = ONE | ((unsigned)sh << 16);  // k10,k11
    e[6] = sl;                          // k12,k13(=0)
    e[7] = 0;                           // k14,k15
}

// ---- precompute: encode pc1 rows (A) and pc2 cols (B) once ----------------
// encA1: p*32 + half*16.  encB2: (p>>5)*1024 + (p&31)*16 (+512 for half 1)
// == LDS ytile layout, so staging is a linear memcpy.
__global__ __launch_bounds__(BLK) void encode_pts(
    const float* __restrict__ pc1, const float* __restrict__ pc2,
    unsigned char* __restrict__ encA1, unsigned char* __restrict__ encB2,
    float* __restrict__ out)
{
    const int gid = blockIdx.x * BLK + threadIdx.x;   // 0 .. 2P-1
    if (gid == 0) out[0] = 0.0f;
    const int p = gid & (P - 1);
    if (gid < P) {
        unsigned ea[8];
        encA(pc1[3 * p], pc1[3 * p + 1], pc1[3 * p + 2], ea);
        unsigned char* ap = encA1 + (size_t)p * 32;
        *(uint4*)(ap)      = make_uint4(ea[0], ea[1], ea[2], ea[3]);
        *(uint4*)(ap + 16) = make_uint4(ea[4], ea[5], ea[6], ea[7]);
    } else {
        unsigned eb[8];
        encB(pc2[3 * p], pc2[3 * p + 1], pc2[3 * p + 2], eb);
        unsigned char* bp = encB2 + (size_t)(p >> 5) * 1024 + (size_t)(p & 31) * 16;
        *(uint4*)(bp)       = make_uint4(eb[0], eb[1], eb[2], eb[3]);
        *(uint4*)(bp + 512) = make_uint4(eb[4], eb[5], eb[6], eb[7]);
    }
}

// ---- main: (row-block, col-segment) sub-matrix; row-min AND col-min --------
__global__ __launch_bounds__(BLK, 4) void chamfer_mfma(
    const unsigned char* __restrict__ encA1,
    const unsigned char* __restrict__ encB2,
    float* __restrict__ part_x,     // [NSEGC][P] row mins, each slot once
    float* __restrict__ part_y)     // [NSLICE][P] col mins, each slot once
{
    const int bx = blockIdx.x;       // 0..63 row block
    const int by = blockIdx.y;       // 0..15 col segment

    __shared__ __align__(16) unsigned char ytile[SEGPTS * 32];  // 32 KB

    const int tid  = threadIdx.x;
    const int lane = tid & 63;
    const int wv   = tid >> 6;
    const int l31  = lane & 31;
    const int half = lane >> 5;          // k-half for A/B frags

    // ---- A fragments: 2 strips of 32 rows per wave, loaded once ----
    const int rowbase = bx * ROWSB + wv * 64;
    const unsigned char* abase = encA1 + (size_t)half * 16;
    const s8v afrag0 = *(const s8v*)(abase + (size_t)(rowbase + l31) * 32);
    const s8v afrag1 = *(const s8v*)(abase + (size_t)(rowbase + 32 + l31) * 32);

    // ---- stage the segment's 1024 col-points: linear coalesced 32 KB copy
    {
        const uint4* gs = (const uint4*)(encB2 + (size_t)(by * SEGPTS) * 32);
        uint4* ls = (uint4*)ytile;
        #pragma unroll
        for (int j = 0; j < 8; ++j) {
            const int idx = tid + j * BLK;        // 2048 x 16B = 32 KB
            ls[idx] = gs[idx];
        }
    }

    f16v acc0, acc1, Z;
    #pragma unroll
    for (int i = 0; i < 16; ++i) { acc0[i] = 3.0e38f; acc1[i] = 3.0e38f; Z[i] = 0.0f; }

    __syncthreads();

    float* ybase = part_y + (size_t)((bx << 2) + wv) * P + by * SEGPTS;
    const unsigned char* rp = ytile + lane * 16;   // conflict-free b128
    for (int t = 0; t < TILES; t += 2) {
        const s8v b0 = *(const s8v*)(rp + t * 1024);
        const s8v b1 = *(const s8v*)(rp + t * 1024 + 1024);
        const f16v d0a = __builtin_amdgcn_mfma_f32_32x32x16_bf16(afrag0, b0, Z, 0, 0, 0);
        const f16v d0b = __builtin_amdgcn_mfma_f32_32x32x16_bf16(afrag0, b1, Z, 0, 0, 0);
        const f16v d1a = __builtin_amdgcn_mfma_f32_32x32x16_bf16(afrag1, b0, Z, 0, 0, 0);
        const f16v d1b = __builtin_amdgcn_mfma_f32_32x32x16_bf16(afrag1, b1, Z, 0, 0, 0);
        // row fold (cham_x)
        #pragma unroll
        for (int i = 0; i < 16; ++i)
            acc0[i] = fminf(acc0[i], fminf(d0a[i], d0b[i]));
        #pragma unroll
        for (int i = 0; i < 16; ++i)
            acc1[i] = fminf(acc1[i], fminf(d1a[i], d1b[i]));
        // col fold (cham_y): tile t over this wave's 64 rows
        {
            float c = fminf(tree16(d0a), tree16(d1a));
            c = fminf(c, __shfl_xor(c, 32, 64));
            if (lane < 32) ybase[t * 32 + l31] = c;
        }
        // col fold: tile t+1
        {
            float c = fminf(tree16(d0b), tree16(d1b));
            c = fminf(c, __shfl_xor(c, 32, 64));
            if (lane < 32) ybase[(t + 1) * 32 + l31] = c;
        }
    }

    // ---- row epilogue: fold over the 32 columns held across lanes ----
    // C/D layout (verified): col=lane&31, row=(reg&3)+8*(reg>>2)+4*(lane>>5)
    float* pbase = part_x + (size_t)by * P;
    #pragma unroll
    for (int s = 0; s < 2; ++s) {
        #pragma unroll
        for (int rg = 0; rg < 16; ++rg) {
            float v = s ? acc1[rg] : acc0[rg];
            v = fminf(v, __shfl_xor(v, 1, 64));
            v = fminf(v, __shfl_xor(v, 2, 64));
            v = fminf(v, __shfl_xor(v, 4, 64));
            v = fminf(v, __shfl_xor(v, 8, 64));
            v = fminf(v, __shfl_xor(v, 16, 64));
            if (l31 == 0) {
                const int row = rowbase + s * 32 + (rg & 3) + 8 * (rg >> 2) + 4 * half;
                pbase[row] = v;
            }
        }
    }
}

// ---- reduce: min over slices, threshold, mean, atomic sum ------------------
__global__ __launch_bounds__(BLK) void chamfer_reduce(
    const float* __restrict__ part_x, const float* __restrict__ part_y,
    float* __restrict__ out)
{
    const int gid = blockIdx.x * BLK + threadIdx.x;   // 0 .. 2P-1
    float m;
    if (gid < P) {                       // cham_x: min over NSEGC row slices
        m = part_x[gid];
        #pragma unroll
        for (int s = 1; s < NSEGC; ++s) m = fminf(m, part_x[(size_t)s * P + gid]);
    } else {                             // cham_y: min over NSLICE col slices
        const int j = gid - P;
        m = part_y[j];
        #pragma unroll 8
        for (int s = 1; s < NSLICE; ++s) m = fminf(m, part_y[(size_t)s * P + j]);
    }

    if (m >= 2.0f) m = 0.0f;                  // DIST_THD mask
    float v = m * (1.0f / (float)P);          // point mean; batch N=1

    #pragma unroll
    for (int off = 32; off > 0; off >>= 1) v += __shfl_down(v, off, 64);

    __shared__ float wsum[BLK / 64];
    const int lane = threadIdx.x & 63;
    const int wvi = threadIdx.x >> 6;
    if (lane == 0) wsum[wvi] = v;
    __syncthreads();
    if (threadIdx.x == 0) {
        float ssum = wsum[0];
        #pragma unroll
        for (int w = 1; w < BLK / 64; ++w) ssum += wsum[w];
        atomicAdd(out, ssum);
    }
}

extern "C" void kernel_launch(void* const* d_in, const int* in_sizes, int n_in,
                              void* d_out, int out_size, void* d_ws, size_t ws_size,
                              hipStream_t stream) {
    const float* pc1 = (const float*)d_in[0];
    const float* pc2 = (const float*)d_in[1];
    float* out = (float*)d_out;
    unsigned char* ws = (unsigned char*)d_ws;
    float* part_x = (float*)ws;                          // 16 x P x 4B = 1 MB
    float* part_y = (float*)(ws + (1u << 20));           // 256 x P x 4B = 16 MB
    unsigned char* encA1 = ws + (17u << 20);             // 512 KB
    unsigned char* encB2 = ws + (17u << 20) + (512u << 10);

    encode_pts<<<(2 * P) / BLK, BLK, 0, stream>>>(pc1, pc2, encA1, encB2, out);

    dim3 grid(NROWB, NSEGC);                  // 64 x 16 = 1024 blocks
    chamfer_mfma<<<grid, BLK, 0, stream>>>(encA1, encB2, part_x, part_y);
    chamfer_reduce<<<(2 * P) / BLK, BLK, 0, stream>>>(part_x, part_y, out);
}